// Round 4
// baseline (651.282 us; speedup 1.0000x reference)
//
#include <hip/hip_runtime.h>
#include <hip/hip_bf16.h>

// Problem constants (fixed by the reference)
#define B_ 8
#define C_ 256
#define E_ 512
#define T_ 8192
#define K_ 512
#define CT_ (C_*T_)
#define CAP_ 32768          // candidate capacity per batch (expected ~4100)
#define SUBS_ 64            // t-subsample stride
#define SCOLS_ (T_/SUBS_)   // 128
#define SUBN_ (E_*SCOLS_)   // 65536 subsample points per batch
#define RANK_ 64            // subsample rank -> expected full count ~4096
#define NB1_ 4096           // subsample histogram bins over [-1,1)
#define NB2_ 4096           // selection histogram bins over [0,0.5)

typedef __attribute__((ext_vector_type(8))) short bf16x8;
typedef __attribute__((ext_vector_type(4))) float f32x4;

__device__ __forceinline__ ushort f2bf(float f) {
    __hip_bfloat16 h = __float2bfloat16(f);
    return *reinterpret_cast<ushort*>(&h);
}
__device__ __forceinline__ float bf2f(ushort u) {
    __hip_bfloat16 h = *reinterpret_cast<__hip_bfloat16*>(&u);
    return __bfloat162float(h);
}

// async global->LDS, 16B per lane; dest = wave-uniform base + lane*16
__device__ __forceinline__ void gl16(const void* g, void* l) {
    __builtin_amdgcn_global_load_lds(
        (const __attribute__((address_space(1))) void*)g,
        (__attribute__((address_space(3))) void*)l, 16, 0, 0);
}

// rn[b,t] = 1/(||x[b,:,t]|| + 1e-8); block 0 also inits Z, cnt
__global__ void k_rn(const float* __restrict__ x, float* __restrict__ rn,
                     float* __restrict__ Z, int* __restrict__ cnt) {
    if (blockIdx.x == 0 && threadIdx.x < B_) {
        Z[threadIdx.x] = 0.f; cnt[threadIdx.x] = 0;
    }
    int gid = blockIdx.x * 256 + threadIdx.x;   // B*T threads
    int b = gid / T_, t = gid % T_;
    const float* xp = x + (size_t)b * CT_ + t;
    float s0 = 0.f, s1 = 0.f, s2 = 0.f, s3 = 0.f;
    for (int c = 0; c < C_; c += 4) {
        float a0 = xp[(size_t)c * T_];
        float a1 = xp[(size_t)(c + 1) * T_];
        float a2 = xp[(size_t)(c + 2) * T_];
        float a3 = xp[(size_t)(c + 3) * T_];
        s0 += a0 * a0; s1 += a1 * a1; s2 += a2 * a2; s3 += a3 * a3;
    }
    float s = (s0 + s1) + (s2 + s3);
    rn[gid] = 1.0f / (sqrtf(s) + 1e-8f);
}

// split mask_w into bf16 hi/lo, same [E][C] layout
__global__ void k_split_w(const float* __restrict__ mw, ushort* __restrict__ mwh,
                          ushort* __restrict__ mwl) {
    int gid = blockIdx.x * 256 + threadIdx.x;   // E*C/4 threads
    float4 v = *(const float4*)(mw + (size_t)gid * 4);
    ushort4 h, l;
    h.x = f2bf(v.x); l.x = f2bf(v.x - bf2f(h.x));
    h.y = f2bf(v.y); l.y = f2bf(v.y - bf2f(h.y));
    h.z = f2bf(v.z); l.z = f2bf(v.z - bf2f(h.z));
    h.w = f2bf(v.w); l.w = f2bf(v.w - bf2f(h.w));
    *(ushort4*)(mwh + (size_t)gid * 4) = h;
    *(ushort4*)(mwl + (size_t)gid * 4) = l;
}

// transpose + rn-scale + split: xh/xl[b][t][c] = bf16split(x[b][c][t]*rn[b][t])
__launch_bounds__(256)
__global__ void k_split_x(const float* __restrict__ x, const float* __restrict__ rn,
                          ushort* __restrict__ xh, ushort* __restrict__ xl) {
    __shared__ float tile[64][76];
    __shared__ float rnv[64];
    int tid = threadIdx.x;
    int t0 = blockIdx.x * 64, c0 = blockIdx.y * 64, b = blockIdx.z;
    if (tid < 64) rnv[tid] = rn[b * T_ + t0 + tid];
    const float* xb = x + (size_t)b * CT_;
#pragma unroll
    for (int q = 0; q < 4; ++q) {
        int idx = tid + q * 256;
        int cr = idx >> 4, t4 = (idx & 15) * 4;
        float4 v = *(const float4*)(xb + (size_t)(c0 + cr) * T_ + t0 + t4);
        *(float4*)&tile[cr][t4] = v;
    }
    __syncthreads();
#pragma unroll
    for (int q = 0; q < 4; ++q) {
        int idx = tid + q * 256;
        int tr = idx >> 4, c4 = (idx & 15) * 4;
        float s = rnv[tr];
        float v0 = tile[c4 + 0][tr] * s;
        float v1 = tile[c4 + 1][tr] * s;
        float v2 = tile[c4 + 2][tr] * s;
        float v3 = tile[c4 + 3][tr] * s;
        ushort4 h, l;
        h.x = f2bf(v0); l.x = f2bf(v0 - bf2f(h.x));
        h.y = f2bf(v1); l.y = f2bf(v1 - bf2f(h.y));
        h.z = f2bf(v2); l.z = f2bf(v2 - bf2f(h.z));
        h.w = f2bf(v3); l.w = f2bf(v3 - bf2f(h.w));
        size_t ro = ((size_t)b * T_ + t0 + tr) * C_ + c0 + c4;
        *(ushort4*)(xh + ro) = h;
        *(ushort4*)(xl + ro) = l;
    }
}

// gather subsampled, rn-scaled x: xs[b][c][s] = x[b][c][s*64] * rn[b][s*64]
__global__ void k_gather(const float* __restrict__ x, const float* __restrict__ rn,
                         float* __restrict__ xs) {
    int gid = blockIdx.x * 256 + threadIdx.x;   // B*C*SCOLS threads = 262144
    int s = gid & (SCOLS_ - 1);
    int c = (gid >> 7) & (C_ - 1);
    int b = gid >> 15;
    int t = s * SUBS_;
    xs[gid] = x[(size_t)b * CT_ + (size_t)c * T_ + t] * rn[b * T_ + t];
}

// tiled f32 GEMM on compact gathered buffer (small: ~270 MFLOP)
__launch_bounds__(256)
__global__ void k_msub2(const float* __restrict__ xs, const float* __restrict__ mw,
                        const float* __restrict__ mb, float* __restrict__ msub) {
    __shared__ float As[64][68];
    __shared__ float Bs[64][68];
    int tid = threadIdx.x;
    int tx = tid & 15, ty = tid >> 4;
    int s0 = blockIdx.x * 64, e0 = blockIdx.y * 64, b = blockIdx.z;
    const float* xb = xs + (size_t)b * C_ * SCOLS_;
    float acc[4][4] = {};
    for (int c0 = 0; c0 < C_; c0 += 64) {
#pragma unroll
        for (int r = 0; r < 4; ++r) {
            int i = (tid >> 4) + r * 16;
            int kq = (tid & 15) * 4;
            float4 av = *(const float4*)(mw + (size_t)(e0 + i) * C_ + c0 + kq);
            As[kq + 0][i] = av.x; As[kq + 1][i] = av.y;
            As[kq + 2][i] = av.z; As[kq + 3][i] = av.w;
        }
#pragma unroll
        for (int r = 0; r < 4; ++r) {
            int k = (tid >> 4) + r * 16;
            int jq = (tid & 15) * 4;
            *(float4*)(&Bs[k][jq]) =
                *(const float4*)(xb + (size_t)(c0 + k) * SCOLS_ + s0 + jq);
        }
        __syncthreads();
#pragma unroll
        for (int k = 0; k < 64; ++k) {
            float4 a = *(const float4*)(&As[k][ty * 4]);
            float4 bq = *(const float4*)(&Bs[k][tx * 4]);
            float av[4] = {a.x, a.y, a.z, a.w};
            float bv[4] = {bq.x, bq.y, bq.z, bq.w};
#pragma unroll
            for (int ii = 0; ii < 4; ++ii)
#pragma unroll
                for (int jj = 0; jj < 4; ++jj)
                    acc[ii][jj] += av[ii] * bv[jj];
        }
        __syncthreads();
    }
#pragma unroll
    for (int ii = 0; ii < 4; ++ii) {
        float mbv = mb[e0 + ty * 4 + ii];
#pragma unroll
        for (int jj = 0; jj < 4; ++jj) {
            int e = e0 + ty * 4 + ii, s = s0 + tx * 4 + jj;
            msub[(size_t)b * SUBN_ + e * SCOLS_ + s] = acc[ii][jj] + mbv;
        }
    }
}

// per-batch conservative threshold tau0 from subsample rank-64
__global__ void k_tau(const float* __restrict__ msub, float* __restrict__ tau0) {
    __shared__ int h[NB1_];
    __shared__ int part[256];
    int b = blockIdx.x, tid = threadIdx.x;
    for (int i = tid; i < NB1_; i += 256) h[i] = 0;
    __syncthreads();
    const float* mp = msub + b * SUBN_;
    for (int j = tid; j < SUBN_; j += 256) {
        float v = mp[j];
        int bin = (int)((v + 1.0f) * ((float)NB1_ * 0.5f));
        bin = bin < 0 ? 0 : (bin > NB1_ - 1 ? NB1_ - 1 : bin);
        atomicAdd(&h[bin], 1);
    }
    __syncthreads();
    int ps = 0;
    for (int j = 0; j < 16; ++j) ps += h[tid * 16 + j];
    part[tid] = ps;
    __syncthreads();
    if (tid == 0) {
        int cum = 0, bf = 0;
        for (int i = 255; i >= 0; --i) {
            if (cum + part[i] >= RANK_) {
                int cum2 = cum;
                for (int j = 15; j >= 0; --j) {
                    cum2 += h[i * 16 + j];
                    if (cum2 >= RANK_) { bf = i * 16 + j; break; }
                }
                break;
            }
            cum += part[i];
        }
        tau0[b] = (float)bf * (2.0f / (float)NB1_) - 1.0f;  // bin lower edge
    }
}

// ---------------- fast main GEMM: precomputed split operands ----------------
// m[b,e,t] = sum_c (mwh+mwl)[e][c]*(xh+xl)[b][t][c] + mb[e] (3-product split);
// Z += sum(__expf(m)); collect m >= tau0.
// LDS: 4 matrices 64x64 u16, XOR-swizzled (cb ^= row&7 per 16B block).
__launch_bounds__(256)
__global__ void k_gemmf(const ushort* __restrict__ mwh, const ushort* __restrict__ mwl,
                        const ushort* __restrict__ xh, const ushort* __restrict__ xl,
                        const float* __restrict__ mb, const float* __restrict__ tau0,
                        float* __restrict__ Z, int* __restrict__ cnt,
                        float* __restrict__ cval, int* __restrict__ cidx) {
    __shared__ ushort S[4][4096];   // Ah, Al, Bh, Bl (each 64 rows x 128 B)
    __shared__ float red[4];
    int tid = threadIdx.x, lane = tid & 63, w = tid >> 6;
    int e0 = blockIdx.x * 64, t0 = blockIdx.y * 64, b = blockIdx.z;

    const ushort* gbase;
    if (w == 0)      gbase = mwh + (size_t)e0 * C_;
    else if (w == 1) gbase = mwl + (size_t)e0 * C_;
    else if (w == 2) gbase = xh + ((size_t)b * T_ + t0) * C_;
    else             gbase = xl + ((size_t)b * T_ + t0) * C_;
    int rsub = lane >> 3;                     // row within 8-row group
    int cbg = (lane & 7) ^ rsub;              // inverse-swizzled source block
    const ushort* gsrc = gbase + (size_t)rsub * C_ + cbg * 8;
    ushort* lbase = &S[w][0];

    f32x4 acc[4] = {{0.f,0.f,0.f,0.f},{0.f,0.f,0.f,0.f},
                    {0.f,0.f,0.f,0.f},{0.f,0.f,0.f,0.f}};
    int a15 = lane & 15;
    int arow = w * 16 + a15;
    int khalf = lane >> 4;                    // 0..3

    for (int cc0 = 0; cc0 < C_; cc0 += 64) {
#pragma unroll
        for (int i = 0; i < 8; ++i)
            gl16(gsrc + cc0 + i * 8 * C_, lbase + i * 512);
        __syncthreads();
#pragma unroll
        for (int ks = 0; ks < 2; ++ks) {
            int cb16 = ks * 4 + khalf;
            const char* Sa = (const char*)&S[0][0];
            const char* Sal = (const char*)&S[1][0];
            int aoff = arow * 128 + ((cb16 ^ (arow & 7)) << 4);
            bf16x8 ah = *(const bf16x8*)(Sa + aoff);
            bf16x8 al = *(const bf16x8*)(Sal + aoff);
#pragma unroll
            for (int n = 0; n < 4; ++n) {
                int brow = n * 16 + a15;
                int boff = brow * 128 + ((cb16 ^ (brow & 7)) << 4);
                bf16x8 bh = *(const bf16x8*)((const char*)&S[2][0] + boff);
                bf16x8 bl = *(const bf16x8*)((const char*)&S[3][0] + boff);
                acc[n] = __builtin_amdgcn_mfma_f32_16x16x32_bf16(ah, bh, acc[n], 0, 0, 0);
                acc[n] = __builtin_amdgcn_mfma_f32_16x16x32_bf16(ah, bl, acc[n], 0, 0, 0);
                acc[n] = __builtin_amdgcn_mfma_f32_16x16x32_bf16(al, bh, acc[n], 0, 0, 0);
            }
        }
        __syncthreads();
    }
    // epilogue: C/D layout col(t)=lane&15, row(e)=(lane>>4)*4+reg
    float tau = tau0[b];
    float zs = 0.f;
    float mbv[4];
#pragma unroll
    for (int r = 0; r < 4; ++r) mbv[r] = mb[e0 + w * 16 + (lane >> 4) * 4 + r];
#pragma unroll
    for (int n = 0; n < 4; ++n) {
        int t = t0 + n * 16 + a15;
#pragma unroll
        for (int r = 0; r < 4; ++r) {
            int e = e0 + w * 16 + (lane >> 4) * 4 + r;
            float v = acc[n][r] + mbv[r];
            zs += __expf(v);
            if (v >= tau) {
                int pos = atomicAdd(&cnt[b], 1);
                if (pos < CAP_) {
                    cval[b * CAP_ + pos] = v;
                    cidx[b * CAP_ + pos] = e * T_ + t;
                }
            }
        }
    }
#pragma unroll
    for (int off = 32; off; off >>= 1) zs += __shfl_xor(zs, off, 64);
    if (lane == 0) red[w] = zs;
    __syncthreads();
    if (tid == 0) atomicAdd(&Z[b], (red[0] + red[1]) + (red[2] + red[3]));
}

// ---------------- fallback main GEMM (R2-proven, used if ws too small) ------
#define PADC 88
__launch_bounds__(256)
__global__ void k_gemm(const float* __restrict__ x, const float* __restrict__ mw,
                       const float* __restrict__ mb, const float* __restrict__ rn,
                       const float* __restrict__ tau0, float* __restrict__ Z,
                       int* __restrict__ cnt, float* __restrict__ cval,
                       int* __restrict__ cidx) {
    __shared__ ushort Ah[64][PADC], Al[64][PADC];
    __shared__ ushort Bh[64][PADC], Bl[64][PADC];
    __shared__ float red[4];
    int tid = threadIdx.x;
    int lane = tid & 63, w = tid >> 6;
    int t0 = blockIdx.x * 64, e0 = blockIdx.y * 64, b = blockIdx.z;
    const float* xb = x + (size_t)b * CT_;
    f32x4 acc[4] = {{0.f,0.f,0.f,0.f},{0.f,0.f,0.f,0.f},
                    {0.f,0.f,0.f,0.f},{0.f,0.f,0.f,0.f}};
    int arow = w * 16 + (lane & 15);
    int koff = (lane >> 4) * 8;

    for (int cc0 = 0; cc0 < C_; cc0 += 64) {
#pragma unroll
        for (int q = 0; q < 4; ++q) {
            int idx = tid + q * 256;
            int er = idx >> 4, c4 = (idx & 15) * 4;
            float4 v = *(const float4*)(mw + (size_t)(e0 + er) * C_ + cc0 + c4);
            ushort4 h, l;
            h.x = f2bf(v.x); l.x = f2bf(v.x - bf2f(h.x));
            h.y = f2bf(v.y); l.y = f2bf(v.y - bf2f(h.y));
            h.z = f2bf(v.z); l.z = f2bf(v.z - bf2f(h.z));
            h.w = f2bf(v.w); l.w = f2bf(v.w - bf2f(h.w));
            *(ushort4*)&Ah[er][c4] = h;
            *(ushort4*)&Al[er][c4] = l;
        }
#pragma unroll
        for (int q = 0; q < 4; ++q) {
            int idx = tid + q * 256;
            int cr = idx >> 4, t4 = (idx & 15) * 4;
            float4 v = *(const float4*)(xb + (size_t)(cc0 + cr) * T_ + t0 + t4);
            float vv[4] = {v.x, v.y, v.z, v.w};
#pragma unroll
            for (int j = 0; j < 4; ++j) {
                ushort h = f2bf(vv[j]);
                Bh[t4 + j][cr] = h;
                Bl[t4 + j][cr] = f2bf(vv[j] - bf2f(h));
            }
        }
        __syncthreads();
#pragma unroll
        for (int ks = 0; ks < 2; ++ks) {
            int cb = ks * 32 + koff;
            bf16x8 ah = *(const bf16x8*)&Ah[arow][cb];
            bf16x8 al = *(const bf16x8*)&Al[arow][cb];
#pragma unroll
            for (int n = 0; n < 4; ++n) {
                int brow = n * 16 + (lane & 15);
                bf16x8 bh = *(const bf16x8*)&Bh[brow][cb];
                bf16x8 bl = *(const bf16x8*)&Bl[brow][cb];
                acc[n] = __builtin_amdgcn_mfma_f32_16x16x32_bf16(ah, bh, acc[n], 0, 0, 0);
                acc[n] = __builtin_amdgcn_mfma_f32_16x16x32_bf16(ah, bl, acc[n], 0, 0, 0);
                acc[n] = __builtin_amdgcn_mfma_f32_16x16x32_bf16(al, bh, acc[n], 0, 0, 0);
            }
        }
        __syncthreads();
    }
    float tau = tau0[b];
    float zs = 0.f;
#pragma unroll
    for (int n = 0; n < 4; ++n) {
        int t = t0 + n * 16 + (lane & 15);
        float rnv = rn[b * T_ + t];
#pragma unroll
        for (int r = 0; r < 4; ++r) {
            int e = e0 + w * 16 + (lane >> 4) * 4 + r;
            float v = acc[n][r] * rnv + mb[e];
            zs += __expf(v);
            if (v >= tau) {
                int pos = atomicAdd(&cnt[b], 1);
                if (pos < CAP_) {
                    cval[b * CAP_ + pos] = v;
                    cidx[b * CAP_ + pos] = e * T_ + t;
                }
            }
        }
    }
#pragma unroll
    for (int off = 32; off; off >>= 1) zs += __shfl_xor(zs, off, 64);
    if (lane == 0) red[w] = zs;
    __syncthreads();
    if (tid == 0) atomicAdd(&Z[b], (red[0] + red[1]) + (red[2] + red[3]));
}

// exact top-K selection among candidates (value desc, index asc on ties)
__launch_bounds__(256)
__global__ void k_select(const float* __restrict__ cval, const int* __restrict__ cidx,
                         const int* __restrict__ cnt, const float* __restrict__ Z,
                         int* __restrict__ sel_e, int* __restrict__ sel_t,
                         float* __restrict__ sel_sp) {
    __shared__ int h[NB2_];
    __shared__ int part[256];
    __shared__ float bl_v[1024];
    __shared__ int bl_i[1024];
    __shared__ int nb, bstar, nabove, outcnt;
    int b = blockIdx.x, tid = threadIdx.x;
    int n = cnt[b]; if (n > CAP_) n = CAP_;
    for (int i = tid; i < NB2_; i += 256) h[i] = 0;
    if (tid == 0) { nb = 0; outcnt = 0; }
    __syncthreads();
    const float* vp = cval + b * CAP_;
    const int* ip = cidx + b * CAP_;
    for (int j = tid; j < n; j += 256) {
        int bin = (int)(vp[j] * ((float)NB2_ * 2.0f));   // [0,0.5) range
        bin = bin < 0 ? 0 : (bin > NB2_ - 1 ? NB2_ - 1 : bin);
        atomicAdd(&h[bin], 1);
    }
    __syncthreads();
    int ps = 0;
    for (int j = 0; j < 16; ++j) ps += h[tid * 16 + j];
    part[tid] = ps;
    __syncthreads();
    if (tid == 0) {
        int cum = 0, bs = 0, na = 0;
        for (int i = 255; i >= 0; --i) {
            if (cum + part[i] >= K_) {
                int cum2 = cum;
                for (int j = 15; j >= 0; --j) {
                    cum2 += h[i * 16 + j];
                    if (cum2 >= K_) { bs = i * 16 + j; na = cum2 - h[i * 16 + j]; break; }
                }
                break;
            }
            cum += part[i];
        }
        bstar = bs; nabove = na;
    }
    __syncthreads();
    int bs = bstar;
    for (int j = tid; j < n; j += 256) {
        float v = vp[j];
        int bin = (int)(v * ((float)NB2_ * 2.0f));
        bin = bin < 0 ? 0 : (bin > NB2_ - 1 ? NB2_ - 1 : bin);
        if (bin == bs) {
            int q = atomicAdd(&nb, 1);
            if (q < 1024) { bl_v[q] = v; bl_i[q] = ip[j]; }
        }
    }
    __syncthreads();
    float rZ = 1.0f / Z[b];
    for (int j = tid; j < n; j += 256) {
        float v = vp[j];
        int bin = (int)(v * ((float)NB2_ * 2.0f));
        bin = bin < 0 ? 0 : (bin > NB2_ - 1 ? NB2_ - 1 : bin);
        if (bin > bs) {
            int q = atomicAdd(&outcnt, 1);
            int idx = ip[j];
            sel_e[b * K_ + q] = idx / T_;
            sel_t[b * K_ + q] = idx % T_;
            sel_sp[b * K_ + q] = __expf(v) * rZ;
        }
    }
    __syncthreads();
    if (tid == 0) {
        int m = nb; if (m > 1024) m = 1024;
        for (int i = 1; i < m; ++i) {          // insertion sort: val desc, idx asc
            float v = bl_v[i]; int id = bl_i[i]; int j = i - 1;
            while (j >= 0 && (bl_v[j] < v || (bl_v[j] == v && bl_i[j] > id))) {
                bl_v[j + 1] = bl_v[j]; bl_i[j + 1] = bl_i[j]; --j;
            }
            bl_v[j + 1] = v; bl_i[j + 1] = id;
        }
        int need = K_ - nabove;
        for (int q = 0; q < need; ++q) {
            int slot = nabove + q;
            if (q < m) {
                int idx = bl_i[q];
                sel_e[b * K_ + slot] = idx / T_;
                sel_t[b * K_ + slot] = idx % T_;
                sel_sp[b * K_ + slot] = __expf(bl_v[q]) * rZ;
            } else {  // pathological fallback: harmless zero entries
                sel_e[b * K_ + slot] = 0; sel_t[b * K_ + slot] = 0;
                sel_sp[b * K_ + slot] = 0.f;
            }
        }
    }
}

// up at selected positions, g = sp * (up + up_b)  (f32 for precision)
__global__ void k_upg(const float* __restrict__ x, const float* __restrict__ uw,
                      const float* __restrict__ ub, const int* __restrict__ sel_e,
                      const int* __restrict__ sel_t, const float* __restrict__ sel_sp,
                      float* __restrict__ gval) {
    int gid = blockIdx.x * 256 + threadIdx.x;   // B*K waves
    int w = gid >> 6, lane = gid & 63;
    int b = w >> 9, i = w & (K_ - 1);
    int e = sel_e[b * K_ + i], t = sel_t[b * K_ + i];
    const float* xp = x + (size_t)b * CT_ + t;
    const float* wp = uw + (size_t)e * C_;
    float acc = 0.f;
    for (int c = lane; c < C_; c += 64) acc += wp[c] * xp[(size_t)c * T_];
    for (int off = 32; off; off >>= 1) acc += __shfl_down(acc, off, 64);
    if (lane == 0) gval[b * K_ + i] = sel_sp[b * K_ + i] * (acc + ub[e]);
}

// merged base + S1/Q: one wave per (b,c)
__global__ void k_bsq(const float* __restrict__ sw, const float* __restrict__ sb,
                      const float* __restrict__ db, const float* __restrict__ dw,
                      const int* __restrict__ sel_e, const float* __restrict__ gval,
                      float* __restrict__ base, float* __restrict__ S1,
                      float* __restrict__ Qv) {
    int wg = blockIdx.x * 4 + (threadIdx.x >> 6);   // 2048 waves
    int lane = threadIdx.x & 63;
    int b = wg >> 8, c = wg & (C_ - 1);
    float p = 0.f, s = 0.f, q = 0.f;
    for (int i = lane; i < K_; i += 64) {
        int e = sel_e[b * K_ + i];
        float g = gval[b * K_ + i];
        p += g * sw[(size_t)c * E_ + e];
        float wv = dw[(size_t)c * E_ + e] * g;
        s += wv; q += wv * wv;
    }
#pragma unroll
    for (int off = 32; off; off >>= 1) {
        p += __shfl_xor(p, off, 64);
        s += __shfl_xor(s, off, 64);
        q += __shfl_xor(q, off, 64);
    }
    if (lane == 0) {
        base[b * C_ + c] = p + sb[c] + db[c];
        S1[b * C_ + c] = s; Qv[b * C_ + c] = q;
    }
}

// BN stats analytic: mean/var per channel, then scale + per-(b,c) output base
__global__ void k_bnstats(const float* __restrict__ base, const float* __restrict__ S1,
                          const float* __restrict__ Qv, const float* __restrict__ bnw,
                          const float* __restrict__ bnb, float* __restrict__ scalec,
                          float* __restrict__ obase) {
    int c = threadIdx.x;
    float msum = 0.f;
    for (int b = 0; b < B_; ++b) msum += (float)T_ * base[b * C_ + c] + S1[b * C_ + c];
    float mean = msum / (float)(B_ * T_);
    float vs = 0.f;
    for (int b = 0; b < B_; ++b) {
        float d = base[b * C_ + c] - mean;
        vs += (float)T_ * d * d + 2.0f * d * S1[b * C_ + c] + Qv[b * C_ + c];
    }
    float var = vs / (float)(B_ * T_);
    float sc = bnw[c] * rsqrtf(var + 1e-5f);
    scalec[c] = sc;
    for (int b = 0; b < B_; ++b)
        obase[b * C_ + c] = (base[b * C_ + c] - mean) * sc + bnb[c];
}

// fill output with column-constant base
__global__ void k_fill(const float* __restrict__ obase, float* __restrict__ out) {
    size_t gid = (size_t)blockIdx.x * 256 + threadIdx.x;
    size_t flat = gid * 4;
    int b = (int)(flat / CT_);
    int c = (int)(flat / T_) & (C_ - 1);
    float v = obase[b * C_ + c];
    float4 o = {v, v, v, v};
    *(float4*)(out + flat) = o;
}

// add spikes: out[b,c,t_i] += scale[c]*down_w[c,e_i]*g_i
__global__ void k_spikes(const float* __restrict__ dw, const float* __restrict__ scalec,
                         const int* __restrict__ sel_e, const int* __restrict__ sel_t,
                         const float* __restrict__ gval, float* __restrict__ out) {
    int gid = blockIdx.x * 256 + threadIdx.x;   // B*K*64 threads
    int s = gid >> 6, cq = (gid & 63) * 4;
    int b = s >> 9, i = s & (K_ - 1);
    int e = sel_e[b * K_ + i], t = sel_t[b * K_ + i];
    float g = gval[b * K_ + i];
#pragma unroll
    for (int q = 0; q < 4; ++q) {
        int c = cq + q;
        atomicAdd(out + (size_t)b * CT_ + (size_t)c * T_ + t,
                  scalec[c] * dw[(size_t)c * E_ + e] * g);
    }
}

extern "C" void kernel_launch(void* const* d_in, const int* in_sizes, int n_in,
                              void* d_out, int out_size, void* d_ws, size_t ws_size,
                              hipStream_t stream) {
    const float* x = (const float*)d_in[0];
    const float* up_w = (const float*)d_in[1];
    const float* up_b = (const float*)d_in[2];
    const float* mask_w = (const float*)d_in[3];
    const float* mask_b = (const float*)d_in[4];
    const float* sum_w = (const float*)d_in[5];
    const float* sum_b = (const float*)d_in[6];
    const float* down_w = (const float*)d_in[7];
    const float* down_b = (const float*)d_in[8];
    const float* bn_w = (const float*)d_in[9];
    const float* bn_b = (const float*)d_in[10];
    float* out = (float*)d_out;

    // workspace layout (float units); small block first, big split buffers last
    float* ws = (float*)d_ws;
    size_t o = 0;
    float* rn = ws + o;   o += (size_t)B_ * T_;
    float* xs = ws + o;   o += (size_t)B_ * C_ * SCOLS_;
    float* msub = ws + o; o += (size_t)B_ * SUBN_;
    float* tau0 = ws + o; o += B_;
    float* Z = ws + o;    o += B_;
    int* cnt = (int*)(ws + o);   o += B_;
    float* cval = ws + o; o += (size_t)B_ * CAP_;
    int* cidx = (int*)(ws + o);  o += (size_t)B_ * CAP_;
    int* sel_e = (int*)(ws + o); o += (size_t)B_ * K_;
    int* sel_t = (int*)(ws + o); o += (size_t)B_ * K_;
    float* sel_sp = ws + o; o += (size_t)B_ * K_;
    float* gval = ws + o;   o += (size_t)B_ * K_;
    float* base = ws + o;   o += (size_t)B_ * C_;
    float* S1 = ws + o;     o += (size_t)B_ * C_;
    float* Qv = ws + o;     o += (size_t)B_ * C_;
    float* scalec = ws + o; o += C_;
    float* obase = ws + o;  o += (size_t)B_ * C_ + 8;
    ushort* mwh = (ushort*)(ws + o); o += (size_t)E_ * C_ / 2;
    ushort* mwl = (ushort*)(ws + o); o += (size_t)E_ * C_ / 2;
    ushort* xh = (ushort*)(ws + o);  o += (size_t)B_ * T_ * C_ / 2;
    ushort* xl = (ushort*)(ws + o);  o += (size_t)B_ * T_ * C_ / 2;
    bool fast = ws_size >= o * sizeof(float);

    k_rn<<<(B_ * T_) / 256, 256, 0, stream>>>(x, rn, Z, cnt);
    k_gather<<<(B_ * C_ * SCOLS_) / 256, 256, 0, stream>>>(x, rn, xs);
    k_msub2<<<dim3(SCOLS_ / 64, E_ / 64, B_), 256, 0, stream>>>(xs, mask_w, mask_b, msub);
    k_tau<<<B_, 256, 0, stream>>>(msub, tau0);
    if (fast) {
        k_split_w<<<(E_ * C_ / 4) / 256, 256, 0, stream>>>(mask_w, mwh, mwl);
        k_split_x<<<dim3(T_ / 64, C_ / 64, B_), 256, 0, stream>>>(x, rn, xh, xl);
        k_gemmf<<<dim3(E_ / 64, T_ / 64, B_), 256, 0, stream>>>(
            mwh, mwl, xh, xl, mask_b, tau0, Z, cnt, cval, cidx);
    } else {
        k_gemm<<<dim3(T_ / 64, E_ / 64, B_), 256, 0, stream>>>(
            x, mask_w, mask_b, rn, tau0, Z, cnt, cval, cidx);
    }
    k_select<<<B_, 256, 0, stream>>>(cval, cidx, cnt, Z, sel_e, sel_t, sel_sp);
    k_upg<<<(B_ * K_ * 64) / 256, 256, 0, stream>>>(x, up_w, up_b, sel_e, sel_t,
                                                    sel_sp, gval);
    k_bsq<<<(B_ * C_) / 4, 256, 0, stream>>>(sum_w, sum_b, down_b, down_w,
                                             sel_e, gval, base, S1, Qv);
    k_bnstats<<<1, C_, 0, stream>>>(base, S1, Qv, bn_w, bn_b, scalec, obase);
    k_fill<<<(B_ * CT_ / 4) / 256, 256, 0, stream>>>(obase, out);
    k_spikes<<<(B_ * K_ * 64) / 256, 256, 0, stream>>>(down_w, scalec, sel_e, sel_t,
                                                       gval, out);
}

// Round 6
// 634.116 us; speedup vs baseline: 1.0271x; 1.0271x over previous
//
#include <hip/hip_runtime.h>
#include <hip/hip_bf16.h>

// Problem constants (fixed by the reference)
#define B_ 8
#define C_ 256
#define E_ 512
#define T_ 8192
#define K_ 512
#define CT_ (C_*T_)
#define CAP_ 32768          // candidate capacity per batch (expected ~4100)
#define SUBS_ 64            // t-subsample stride
#define SCOLS_ (T_/SUBS_)   // 128
#define SUBN_ (E_*SCOLS_)   // 65536 subsample points per batch
#define RANK_ 64            // subsample rank -> expected full count ~4096
#define NB1_ 4096           // subsample histogram bins over [-1,1)
#define NB2_ 4096           // selection histogram bins over [0,0.5)

typedef __attribute__((ext_vector_type(8))) short bf16x8;
typedef __attribute__((ext_vector_type(4))) float f32x4;

__device__ __forceinline__ ushort f2bf(float f) {
    __hip_bfloat16 h = __float2bfloat16(f);
    return *reinterpret_cast<ushort*>(&h);
}
__device__ __forceinline__ float bf2f(ushort u) {
    __hip_bfloat16 h = *reinterpret_cast<__hip_bfloat16*>(&u);
    return __bfloat162float(h);
}

// async global->LDS, 16B per lane; dest = wave-uniform base + lane*16
__device__ __forceinline__ void gl16(const void* g, void* l) {
    __builtin_amdgcn_global_load_lds(
        (const __attribute__((address_space(1))) void*)g,
        (__attribute__((address_space(3))) void*)l, 16, 0, 0);
}

// rn[b,t] = 1/(||x[b,:,t]|| + 1e-8); nrm = ||x|| + 1e-8; block 0 inits Z, cnt
__global__ void k_rn(const float* __restrict__ x, float* __restrict__ rn,
                     float* __restrict__ nrm, float* __restrict__ Z,
                     int* __restrict__ cnt) {
    if (blockIdx.x == 0 && threadIdx.x < B_) {
        Z[threadIdx.x] = 0.f; cnt[threadIdx.x] = 0;
    }
    int gid = blockIdx.x * 256 + threadIdx.x;   // B*T threads
    int b = gid / T_, t = gid % T_;
    const float* xp = x + (size_t)b * CT_ + t;
    float s0 = 0.f, s1 = 0.f, s2 = 0.f, s3 = 0.f;
    for (int c = 0; c < C_; c += 4) {
        float a0 = xp[(size_t)c * T_];
        float a1 = xp[(size_t)(c + 1) * T_];
        float a2 = xp[(size_t)(c + 2) * T_];
        float a3 = xp[(size_t)(c + 3) * T_];
        s0 += a0 * a0; s1 += a1 * a1; s2 += a2 * a2; s3 += a3 * a3;
    }
    float s = (s0 + s1) + (s2 + s3);
    float n = sqrtf(s) + 1e-8f;
    nrm[gid] = n;
    rn[gid] = 1.0f / n;
}

// split mask_w into bf16 hi/lo, same [E][C] layout
__global__ void k_split_w(const float* __restrict__ mw, ushort* __restrict__ mwh,
                          ushort* __restrict__ mwl) {
    int gid = blockIdx.x * 256 + threadIdx.x;   // E*C/4 threads
    float4 v = *(const float4*)(mw + (size_t)gid * 4);
    ushort4 h, l;
    h.x = f2bf(v.x); l.x = f2bf(v.x - bf2f(h.x));
    h.y = f2bf(v.y); l.y = f2bf(v.y - bf2f(h.y));
    h.z = f2bf(v.z); l.z = f2bf(v.z - bf2f(h.z));
    h.w = f2bf(v.w); l.w = f2bf(v.w - bf2f(h.w));
    *(ushort4*)(mwh + (size_t)gid * 4) = h;
    *(ushort4*)(mwl + (size_t)gid * 4) = l;
}

// transpose + rn-scale + split: xh/xl[b][t][c] = bf16split(x[b][c][t]*rn[b][t])
__launch_bounds__(256)
__global__ void k_split_x(const float* __restrict__ x, const float* __restrict__ rn,
                          ushort* __restrict__ xh, ushort* __restrict__ xl) {
    __shared__ float tile[64][76];
    __shared__ float rnv[64];
    int tid = threadIdx.x;
    int t0 = blockIdx.x * 64, c0 = blockIdx.y * 64, b = blockIdx.z;
    if (tid < 64) rnv[tid] = rn[b * T_ + t0 + tid];
    const float* xb = x + (size_t)b * CT_;
#pragma unroll
    for (int q = 0; q < 4; ++q) {
        int idx = tid + q * 256;
        int cr = idx >> 4, t4 = (idx & 15) * 4;
        float4 v = *(const float4*)(xb + (size_t)(c0 + cr) * T_ + t0 + t4);
        *(float4*)&tile[cr][t4] = v;
    }
    __syncthreads();
#pragma unroll
    for (int q = 0; q < 4; ++q) {
        int idx = tid + q * 256;
        int tr = idx >> 4, c4 = (idx & 15) * 4;
        float s = rnv[tr];
        float v0 = tile[c4 + 0][tr] * s;
        float v1 = tile[c4 + 1][tr] * s;
        float v2 = tile[c4 + 2][tr] * s;
        float v3 = tile[c4 + 3][tr] * s;
        ushort4 h, l;
        h.x = f2bf(v0); l.x = f2bf(v0 - bf2f(h.x));
        h.y = f2bf(v1); l.y = f2bf(v1 - bf2f(h.y));
        h.z = f2bf(v2); l.z = f2bf(v2 - bf2f(h.z));
        h.w = f2bf(v3); l.w = f2bf(v3 - bf2f(h.w));
        size_t ro = ((size_t)b * T_ + t0 + tr) * C_ + c0 + c4;
        *(ushort4*)(xh + ro) = h;
        *(ushort4*)(xl + ro) = l;
    }
}

// gather subsampled, rn-scaled x: xs[b][c][s] = x[b][c][s*64] * rn[b][s*64]
__global__ void k_gather(const float* __restrict__ x, const float* __restrict__ rn,
                         float* __restrict__ xs) {
    int gid = blockIdx.x * 256 + threadIdx.x;   // B*C*SCOLS threads = 262144
    int s = gid & (SCOLS_ - 1);
    int c = (gid >> 7) & (C_ - 1);
    int b = gid >> 15;
    int t = s * SUBS_;
    xs[gid] = x[(size_t)b * CT_ + (size_t)c * T_ + t] * rn[b * T_ + t];
}

// tiled f32 GEMM on compact gathered buffer (small: ~270 MFLOP)
__launch_bounds__(256)
__global__ void k_msub2(const float* __restrict__ xs, const float* __restrict__ mw,
                        const float* __restrict__ mb, float* __restrict__ msub) {
    __shared__ float As[64][68];
    __shared__ float Bs[64][68];
    int tid = threadIdx.x;
    int tx = tid & 15, ty = tid >> 4;
    int s0 = blockIdx.x * 64, e0 = blockIdx.y * 64, b = blockIdx.z;
    const float* xb = xs + (size_t)b * C_ * SCOLS_;
    float acc[4][4] = {};
    for (int c0 = 0; c0 < C_; c0 += 64) {
#pragma unroll
        for (int r = 0; r < 4; ++r) {
            int i = (tid >> 4) + r * 16;
            int kq = (tid & 15) * 4;
            float4 av = *(const float4*)(mw + (size_t)(e0 + i) * C_ + c0 + kq);
            As[kq + 0][i] = av.x; As[kq + 1][i] = av.y;
            As[kq + 2][i] = av.z; As[kq + 3][i] = av.w;
        }
#pragma unroll
        for (int r = 0; r < 4; ++r) {
            int k = (tid >> 4) + r * 16;
            int jq = (tid & 15) * 4;
            *(float4*)(&Bs[k][jq]) =
                *(const float4*)(xb + (size_t)(c0 + k) * SCOLS_ + s0 + jq);
        }
        __syncthreads();
#pragma unroll
        for (int k = 0; k < 64; ++k) {
            float4 a = *(const float4*)(&As[k][ty * 4]);
            float4 bq = *(const float4*)(&Bs[k][tx * 4]);
            float av[4] = {a.x, a.y, a.z, a.w};
            float bv[4] = {bq.x, bq.y, bq.z, bq.w};
#pragma unroll
            for (int ii = 0; ii < 4; ++ii)
#pragma unroll
                for (int jj = 0; jj < 4; ++jj)
                    acc[ii][jj] += av[ii] * bv[jj];
        }
        __syncthreads();
    }
#pragma unroll
    for (int ii = 0; ii < 4; ++ii) {
        float mbv = mb[e0 + ty * 4 + ii];
#pragma unroll
        for (int jj = 0; jj < 4; ++jj) {
            int e = e0 + ty * 4 + ii, s = s0 + tx * 4 + jj;
            msub[(size_t)b * SUBN_ + e * SCOLS_ + s] = acc[ii][jj] + mbv;
        }
    }
}

// per-batch conservative threshold tau0 from subsample rank-64
__global__ void k_tau(const float* __restrict__ msub, float* __restrict__ tau0) {
    __shared__ int h[NB1_];
    __shared__ int part[256];
    int b = blockIdx.x, tid = threadIdx.x;
    for (int i = tid; i < NB1_; i += 256) h[i] = 0;
    __syncthreads();
    const float* mp = msub + b * SUBN_;
    for (int j = tid; j < SUBN_; j += 256) {
        float v = mp[j];
        int bin = (int)((v + 1.0f) * ((float)NB1_ * 0.5f));
        bin = bin < 0 ? 0 : (bin > NB1_ - 1 ? NB1_ - 1 : bin);
        atomicAdd(&h[bin], 1);
    }
    __syncthreads();
    int ps = 0;
    for (int j = 0; j < 16; ++j) ps += h[tid * 16 + j];
    part[tid] = ps;
    __syncthreads();
    if (tid == 0) {
        int cum = 0, bf = 0;
        for (int i = 255; i >= 0; --i) {
            if (cum + part[i] >= RANK_) {
                int cum2 = cum;
                for (int j = 15; j >= 0; --j) {
                    cum2 += h[i * 16 + j];
                    if (cum2 >= RANK_) { bf = i * 16 + j; break; }
                }
                break;
            }
            cum += part[i];
        }
        tau0[b] = (float)bf * (2.0f / (float)NB1_) - 1.0f;  // bin lower edge
    }
}

// ---------------- fast main GEMM: split operands, XCD-grouped ----------------
// R3-proven single-buffer body (replay-safe: each chunk is gl16 -> barrier
// (vmcnt drained) -> MFMA -> barrier). Only the block-index decode changed:
// flat grid 8192; blockIdx%8 (=XCD) owns contiguous x-tiles, and the 8
// e-blocks of each x-tile sit on adjacent slots of the SAME XCD (L2 reuse).
__launch_bounds__(256)
__global__ void k_gemmf(const ushort* __restrict__ mwh, const ushort* __restrict__ mwl,
                        const ushort* __restrict__ xh, const ushort* __restrict__ xl,
                        const float* __restrict__ mb, const float* __restrict__ tau0,
                        float* __restrict__ Z, int* __restrict__ cnt,
                        float* __restrict__ cval, int* __restrict__ cidx) {
    __shared__ ushort S[4][4096];   // Ah, Al, Bh, Bl (each 64 rows x 128 B)
    __shared__ float red[4];
    int tid = threadIdx.x, lane = tid & 63, w = tid >> 6;
    int f = blockIdx.x;
    int xcd = f & 7, slot = f >> 3;          // presumed XCD round-robin
    int xtile = xcd * 128 + (slot >> 3);     // 0..1023 = b*128 + t-tile
    int e0 = (slot & 7) * 64;                // e-block fastest within XCD
    int b = xtile >> 7;
    int t0 = (xtile & 127) * 64;

    const ushort* gbase;
    if (w == 0)      gbase = mwh + (size_t)e0 * C_;
    else if (w == 1) gbase = mwl + (size_t)e0 * C_;
    else if (w == 2) gbase = xh + ((size_t)b * T_ + t0) * C_;
    else             gbase = xl + ((size_t)b * T_ + t0) * C_;
    int rsub = lane >> 3;                     // row within 8-row group
    int cbg = (lane & 7) ^ rsub;              // inverse-swizzled source block
    const ushort* gsrc = gbase + (size_t)rsub * C_ + cbg * 8;
    ushort* lbase = &S[w][0];

    f32x4 acc[4] = {{0.f,0.f,0.f,0.f},{0.f,0.f,0.f,0.f},
                    {0.f,0.f,0.f,0.f},{0.f,0.f,0.f,0.f}};
    int a15 = lane & 15;
    int arow = w * 16 + a15;
    int khalf = lane >> 4;                    // 0..3

    for (int cc0 = 0; cc0 < C_; cc0 += 64) {
#pragma unroll
        for (int i = 0; i < 8; ++i)
            gl16(gsrc + cc0 + i * 8 * C_, lbase + i * 512);
        __syncthreads();
#pragma unroll
        for (int ks = 0; ks < 2; ++ks) {
            int cb16 = ks * 4 + khalf;
            const char* Sa = (const char*)&S[0][0];
            const char* Sal = (const char*)&S[1][0];
            int aoff = arow * 128 + ((cb16 ^ (arow & 7)) << 4);
            bf16x8 ah = *(const bf16x8*)(Sa + aoff);
            bf16x8 al = *(const bf16x8*)(Sal + aoff);
#pragma unroll
            for (int n = 0; n < 4; ++n) {
                int brow = n * 16 + a15;
                int boff = brow * 128 + ((cb16 ^ (brow & 7)) << 4);
                bf16x8 bh = *(const bf16x8*)((const char*)&S[2][0] + boff);
                bf16x8 bl = *(const bf16x8*)((const char*)&S[3][0] + boff);
                acc[n] = __builtin_amdgcn_mfma_f32_16x16x32_bf16(ah, bh, acc[n], 0, 0, 0);
                acc[n] = __builtin_amdgcn_mfma_f32_16x16x32_bf16(ah, bl, acc[n], 0, 0, 0);
                acc[n] = __builtin_amdgcn_mfma_f32_16x16x32_bf16(al, bh, acc[n], 0, 0, 0);
            }
        }
        __syncthreads();
    }
    // epilogue: C/D layout col(t)=lane&15, row(e)=(lane>>4)*4+reg
    float tau = tau0[b];
    float zs = 0.f;
    float mbv[4];
#pragma unroll
    for (int r = 0; r < 4; ++r) mbv[r] = mb[e0 + w * 16 + (lane >> 4) * 4 + r];
#pragma unroll
    for (int n = 0; n < 4; ++n) {
        int t = t0 + n * 16 + a15;
#pragma unroll
        for (int r = 0; r < 4; ++r) {
            int e = e0 + w * 16 + (lane >> 4) * 4 + r;
            float v = acc[n][r] + mbv[r];
            zs += __expf(v);
            if (v >= tau) {
                int pos = atomicAdd(&cnt[b], 1);
                if (pos < CAP_) {
                    cval[b * CAP_ + pos] = v;
                    cidx[b * CAP_ + pos] = e * T_ + t;
                }
            }
        }
    }
#pragma unroll
    for (int off = 32; off; off >>= 1) zs += __shfl_xor(zs, off, 64);
    if (lane == 0) red[w] = zs;
    __syncthreads();
    if (tid == 0) atomicAdd(&Z[b], (red[0] + red[1]) + (red[2] + red[3]));
}

// ---------------- fallback main GEMM (R2-proven, used if ws too small) ------
#define PADC 88
__launch_bounds__(256)
__global__ void k_gemm(const float* __restrict__ x, const float* __restrict__ mw,
                       const float* __restrict__ mb, const float* __restrict__ rn,
                       const float* __restrict__ tau0, float* __restrict__ Z,
                       int* __restrict__ cnt, float* __restrict__ cval,
                       int* __restrict__ cidx) {
    __shared__ ushort Ah[64][PADC], Al[64][PADC];
    __shared__ ushort Bh[64][PADC], Bl[64][PADC];
    __shared__ float red[4];
    int tid = threadIdx.x;
    int lane = tid & 63, w = tid >> 6;
    int t0 = blockIdx.x * 64, e0 = blockIdx.y * 64, b = blockIdx.z;
    const float* xb = x + (size_t)b * CT_;
    f32x4 acc[4] = {{0.f,0.f,0.f,0.f},{0.f,0.f,0.f,0.f},
                    {0.f,0.f,0.f,0.f},{0.f,0.f,0.f,0.f}};
    int arow = w * 16 + (lane & 15);
    int koff = (lane >> 4) * 8;

    for (int cc0 = 0; cc0 < C_; cc0 += 64) {
#pragma unroll
        for (int q = 0; q < 4; ++q) {
            int idx = tid + q * 256;
            int er = idx >> 4, c4 = (idx & 15) * 4;
            float4 v = *(const float4*)(mw + (size_t)(e0 + er) * C_ + cc0 + c4);
            ushort4 h, l;
            h.x = f2bf(v.x); l.x = f2bf(v.x - bf2f(h.x));
            h.y = f2bf(v.y); l.y = f2bf(v.y - bf2f(h.y));
            h.z = f2bf(v.z); l.z = f2bf(v.z - bf2f(h.z));
            h.w = f2bf(v.w); l.w = f2bf(v.w - bf2f(h.w));
            *(ushort4*)&Ah[er][c4] = h;
            *(ushort4*)&Al[er][c4] = l;
        }
#pragma unroll
        for (int q = 0; q < 4; ++q) {
            int idx = tid + q * 256;
            int cr = idx >> 4, t4 = (idx & 15) * 4;
            float4 v = *(const float4*)(xb + (size_t)(cc0 + cr) * T_ + t0 + t4);
            float vv[4] = {v.x, v.y, v.z, v.w};
#pragma unroll
            for (int j = 0; j < 4; ++j) {
                ushort h = f2bf(vv[j]);
                Bh[t4 + j][cr] = h;
                Bl[t4 + j][cr] = f2bf(vv[j] - bf2f(h));
            }
        }
        __syncthreads();
#pragma unroll
        for (int ks = 0; ks < 2; ++ks) {
            int cb = ks * 32 + koff;
            bf16x8 ah = *(const bf16x8*)&Ah[arow][cb];
            bf16x8 al = *(const bf16x8*)&Al[arow][cb];
#pragma unroll
            for (int n = 0; n < 4; ++n) {
                int brow = n * 16 + (lane & 15);
                bf16x8 bh = *(const bf16x8*)&Bh[brow][cb];
                bf16x8 bl = *(const bf16x8*)&Bl[brow][cb];
                acc[n] = __builtin_amdgcn_mfma_f32_16x16x32_bf16(ah, bh, acc[n], 0, 0, 0);
                acc[n] = __builtin_amdgcn_mfma_f32_16x16x32_bf16(ah, bl, acc[n], 0, 0, 0);
                acc[n] = __builtin_amdgcn_mfma_f32_16x16x32_bf16(al, bh, acc[n], 0, 0, 0);
            }
        }
        __syncthreads();
    }
    float tau = tau0[b];
    float zs = 0.f;
#pragma unroll
    for (int n = 0; n < 4; ++n) {
        int t = t0 + n * 16 + (lane & 15);
        float rnv = rn[b * T_ + t];
#pragma unroll
        for (int r = 0; r < 4; ++r) {
            int e = e0 + w * 16 + (lane >> 4) * 4 + r;
            float v = acc[n][r] * rnv + mb[e];
            zs += __expf(v);
            if (v >= tau) {
                int pos = atomicAdd(&cnt[b], 1);
                if (pos < CAP_) {
                    cval[b * CAP_ + pos] = v;
                    cidx[b * CAP_ + pos] = e * T_ + t;
                }
            }
        }
    }
#pragma unroll
    for (int off = 32; off; off >>= 1) zs += __shfl_xor(zs, off, 64);
    if (lane == 0) red[w] = zs;
    __syncthreads();
    if (tid == 0) atomicAdd(&Z[b], (red[0] + red[1]) + (red[2] + red[3]));
}

// exact top-K selection among candidates (value desc, index asc on ties)
__launch_bounds__(256)
__global__ void k_select(const float* __restrict__ cval, const int* __restrict__ cidx,
                         const int* __restrict__ cnt, const float* __restrict__ Z,
                         int* __restrict__ sel_e, int* __restrict__ sel_t,
                         float* __restrict__ sel_sp) {
    __shared__ int h[NB2_];
    __shared__ int part[256];
    __shared__ float bl_v[1024];
    __shared__ int bl_i[1024];
    __shared__ int nb, bstar, nabove, outcnt;
    int b = blockIdx.x, tid = threadIdx.x;
    int n = cnt[b]; if (n > CAP_) n = CAP_;
    for (int i = tid; i < NB2_; i += 256) h[i] = 0;
    if (tid == 0) { nb = 0; outcnt = 0; }
    __syncthreads();
    const float* vp = cval + b * CAP_;
    const int* ip = cidx + b * CAP_;
    for (int j = tid; j < n; j += 256) {
        int bin = (int)(vp[j] * ((float)NB2_ * 2.0f));   // [0,0.5) range
        bin = bin < 0 ? 0 : (bin > NB2_ - 1 ? NB2_ - 1 : bin);
        atomicAdd(&h[bin], 1);
    }
    __syncthreads();
    int ps = 0;
    for (int j = 0; j < 16; ++j) ps += h[tid * 16 + j];
    part[tid] = ps;
    __syncthreads();
    if (tid == 0) {
        int cum = 0, bs = 0, na = 0;
        for (int i = 255; i >= 0; --i) {
            if (cum + part[i] >= K_) {
                int cum2 = cum;
                for (int j = 15; j >= 0; --j) {
                    cum2 += h[i * 16 + j];
                    if (cum2 >= K_) { bs = i * 16 + j; na = cum2 - h[i * 16 + j]; break; }
                }
                break;
            }
            cum += part[i];
        }
        bstar = bs; nabove = na;
    }
    __syncthreads();
    int bs = bstar;
    for (int j = tid; j < n; j += 256) {
        float v = vp[j];
        int bin = (int)(v * ((float)NB2_ * 2.0f));
        bin = bin < 0 ? 0 : (bin > NB2_ - 1 ? NB2_ - 1 : bin);
        if (bin == bs) {
            int q = atomicAdd(&nb, 1);
            if (q < 1024) { bl_v[q] = v; bl_i[q] = ip[j]; }
        }
    }
    __syncthreads();
    float rZ = 1.0f / Z[b];
    for (int j = tid; j < n; j += 256) {
        float v = vp[j];
        int bin = (int)(v * ((float)NB2_ * 2.0f));
        bin = bin < 0 ? 0 : (bin > NB2_ - 1 ? NB2_ - 1 : bin);
        if (bin > bs) {
            int q = atomicAdd(&outcnt, 1);
            int idx = ip[j];
            sel_e[b * K_ + q] = idx / T_;
            sel_t[b * K_ + q] = idx % T_;
            sel_sp[b * K_ + q] = __expf(v) * rZ;
        }
    }
    __syncthreads();
    if (tid == 0) {
        int m = nb; if (m > 1024) m = 1024;
        for (int i = 1; i < m; ++i) {          // insertion sort: val desc, idx asc
            float v = bl_v[i]; int id = bl_i[i]; int j = i - 1;
            while (j >= 0 && (bl_v[j] < v || (bl_v[j] == v && bl_i[j] > id))) {
                bl_v[j + 1] = bl_v[j]; bl_i[j + 1] = bl_i[j]; --j;
            }
            bl_v[j + 1] = v; bl_i[j + 1] = id;
        }
        int need = K_ - nabove;
        for (int q = 0; q < need; ++q) {
            int slot = nabove + q;
            if (q < m) {
                int idx = bl_i[q];
                sel_e[b * K_ + slot] = idx / T_;
                sel_t[b * K_ + slot] = idx % T_;
                sel_sp[b * K_ + slot] = __expf(bl_v[q]) * rZ;
            } else {  // pathological fallback: harmless zero entries
                sel_e[b * K_ + slot] = 0; sel_t[b * K_ + slot] = 0;
                sel_sp[b * K_ + slot] = 0.f;
            }
        }
    }
}

// up at selected positions via transposed split-x (coalesced in c):
// up.x = (sum_c uw[c]*(xh+xl)[t][c]) * nrm[t];  g = sp * (up + up_b)
__global__ void k_upg2(const ushort* __restrict__ xh, const ushort* __restrict__ xl,
                       const float* __restrict__ nrm, const float* __restrict__ uw,
                       const float* __restrict__ ub, const int* __restrict__ sel_e,
                       const int* __restrict__ sel_t, const float* __restrict__ sel_sp,
                       float* __restrict__ gval) {
    int gid = blockIdx.x * 256 + threadIdx.x;   // B*K waves
    int w = gid >> 6, lane = gid & 63;
    int b = w >> 9, i = w & (K_ - 1);
    int e = sel_e[b * K_ + i], t = sel_t[b * K_ + i];
    size_t ro = ((size_t)b * T_ + t) * C_ + lane * 4;
    ushort4 h = *(const ushort4*)(xh + ro);
    ushort4 l = *(const ushort4*)(xl + ro);
    float4 wv = *(const float4*)(uw + (size_t)e * C_ + lane * 4);
    float acc = (bf2f(h.x) + bf2f(l.x)) * wv.x + (bf2f(h.y) + bf2f(l.y)) * wv.y
              + (bf2f(h.z) + bf2f(l.z)) * wv.z + (bf2f(h.w) + bf2f(l.w)) * wv.w;
#pragma unroll
    for (int off = 32; off; off >>= 1) acc += __shfl_down(acc, off, 64);
    if (lane == 0)
        gval[b * K_ + i] = sel_sp[b * K_ + i] * (acc * nrm[b * T_ + t] + ub[e]);
}

// fallback k_upg (raw x, strided)
__global__ void k_upg(const float* __restrict__ x, const float* __restrict__ uw,
                      const float* __restrict__ ub, const int* __restrict__ sel_e,
                      const int* __restrict__ sel_t, const float* __restrict__ sel_sp,
                      float* __restrict__ gval) {
    int gid = blockIdx.x * 256 + threadIdx.x;   // B*K waves
    int w = gid >> 6, lane = gid & 63;
    int b = w >> 9, i = w & (K_ - 1);
    int e = sel_e[b * K_ + i], t = sel_t[b * K_ + i];
    const float* xp = x + (size_t)b * CT_ + t;
    const float* wp = uw + (size_t)e * C_;
    float acc = 0.f;
    for (int c = lane; c < C_; c += 64) acc += wp[c] * xp[(size_t)c * T_];
    for (int off = 32; off; off >>= 1) acc += __shfl_down(acc, off, 64);
    if (lane == 0) gval[b * K_ + i] = sel_sp[b * K_ + i] * (acc + ub[e]);
}

// merged base + S1/Q: one wave per (b,c)
__global__ void k_bsq(const float* __restrict__ sw, const float* __restrict__ sb,
                      const float* __restrict__ db, const float* __restrict__ dw,
                      const int* __restrict__ sel_e, const float* __restrict__ gval,
                      float* __restrict__ base, float* __restrict__ S1,
                      float* __restrict__ Qv) {
    int wg = blockIdx.x * 4 + (threadIdx.x >> 6);   // 2048 waves
    int lane = threadIdx.x & 63;
    int b = wg >> 8, c = wg & (C_ - 1);
    float p = 0.f, s = 0.f, q = 0.f;
    for (int i = lane; i < K_; i += 64) {
        int e = sel_e[b * K_ + i];
        float g = gval[b * K_ + i];
        p += g * sw[(size_t)c * E_ + e];
        float wv = dw[(size_t)c * E_ + e] * g;
        s += wv; q += wv * wv;
    }
#pragma unroll
    for (int off = 32; off; off >>= 1) {
        p += __shfl_xor(p, off, 64);
        s += __shfl_xor(s, off, 64);
        q += __shfl_xor(q, off, 64);
    }
    if (lane == 0) {
        base[b * C_ + c] = p + sb[c] + db[c];
        S1[b * C_ + c] = s; Qv[b * C_ + c] = q;
    }
}

// BN stats analytic: mean/var per channel, then scale + per-(b,c) output base
__global__ void k_bnstats(const float* __restrict__ base, const float* __restrict__ S1,
                          const float* __restrict__ Qv, const float* __restrict__ bnw,
                          const float* __restrict__ bnb, float* __restrict__ scalec,
                          float* __restrict__ obase) {
    int c = threadIdx.x;
    float msum = 0.f;
    for (int b = 0; b < B_; ++b) msum += (float)T_ * base[b * C_ + c] + S1[b * C_ + c];
    float mean = msum / (float)(B_ * T_);
    float vs = 0.f;
    for (int b = 0; b < B_; ++b) {
        float d = base[b * C_ + c] - mean;
        vs += (float)T_ * d * d + 2.0f * d * S1[b * C_ + c] + Qv[b * C_ + c];
    }
    float var = vs / (float)(B_ * T_);
    float sc = bnw[c] * rsqrtf(var + 1e-5f);
    scalec[c] = sc;
    for (int b = 0; b < B_; ++b)
        obase[b * C_ + c] = (base[b * C_ + c] - mean) * sc + bnb[c];
}

// fill output with column-constant base
__global__ void k_fill(const float* __restrict__ obase, float* __restrict__ out) {
    size_t gid = (size_t)blockIdx.x * 256 + threadIdx.x;
    size_t flat = gid * 4;
    int b = (int)(flat / CT_);
    int c = (int)(flat / T_) & (C_ - 1);
    float v = obase[b * C_ + c];
    float4 o = {v, v, v, v};
    *(float4*)(out + flat) = o;
}

// add spikes: out[b,c,t_i] += scale[c]*down_w[c,e_i]*g_i
__global__ void k_spikes(const float* __restrict__ dw, const float* __restrict__ scalec,
                         const int* __restrict__ sel_e, const int* __restrict__ sel_t,
                         const float* __restrict__ gval, float* __restrict__ out) {
    int gid = blockIdx.x * 256 + threadIdx.x;   // B*K*64 threads
    int s = gid >> 6, cq = (gid & 63) * 4;
    int b = s >> 9, i = s & (K_ - 1);
    int e = sel_e[b * K_ + i], t = sel_t[b * K_ + i];
    float g = gval[b * K_ + i];
#pragma unroll
    for (int q = 0; q < 4; ++q) {
        int c = cq + q;
        atomicAdd(out + (size_t)b * CT_ + (size_t)c * T_ + t,
                  scalec[c] * dw[(size_t)c * E_ + e] * g);
    }
}

extern "C" void kernel_launch(void* const* d_in, const int* in_sizes, int n_in,
                              void* d_out, int out_size, void* d_ws, size_t ws_size,
                              hipStream_t stream) {
    const float* x = (const float*)d_in[0];
    const float* up_w = (const float*)d_in[1];
    const float* up_b = (const float*)d_in[2];
    const float* mask_w = (const float*)d_in[3];
    const float* mask_b = (const float*)d_in[4];
    const float* sum_w = (const float*)d_in[5];
    const float* sum_b = (const float*)d_in[6];
    const float* down_w = (const float*)d_in[7];
    const float* down_b = (const float*)d_in[8];
    const float* bn_w = (const float*)d_in[9];
    const float* bn_b = (const float*)d_in[10];
    float* out = (float*)d_out;

    // workspace layout (float units); small block first, big split buffers last
    float* ws = (float*)d_ws;
    size_t o = 0;
    float* rn = ws + o;   o += (size_t)B_ * T_;
    float* nrm = ws + o;  o += (size_t)B_ * T_;
    float* xs = ws + o;   o += (size_t)B_ * C_ * SCOLS_;
    float* msub = ws + o; o += (size_t)B_ * SUBN_;
    float* tau0 = ws + o; o += B_;
    float* Z = ws + o;    o += B_;
    int* cnt = (int*)(ws + o);   o += B_;
    float* cval = ws + o; o += (size_t)B_ * CAP_;
    int* cidx = (int*)(ws + o);  o += (size_t)B_ * CAP_;
    int* sel_e = (int*)(ws + o); o += (size_t)B_ * K_;
    int* sel_t = (int*)(ws + o); o += (size_t)B_ * K_;
    float* sel_sp = ws + o; o += (size_t)B_ * K_;
    float* gval = ws + o;   o += (size_t)B_ * K_;
    float* base = ws + o;   o += (size_t)B_ * C_;
    float* S1 = ws + o;     o += (size_t)B_ * C_;
    float* Qv = ws + o;     o += (size_t)B_ * C_;
    float* scalec = ws + o; o += C_;
    float* obase = ws + o;  o += (size_t)B_ * C_ + 8;
    ushort* mwh = (ushort*)(ws + o); o += (size_t)E_ * C_ / 2;
    ushort* mwl = (ushort*)(ws + o); o += (size_t)E_ * C_ / 2;
    ushort* xh = (ushort*)(ws + o);  o += (size_t)B_ * T_ * C_ / 2;
    ushort* xl = (ushort*)(ws + o);  o += (size_t)B_ * T_ * C_ / 2;
    bool fast = ws_size >= o * sizeof(float);

    k_rn<<<(B_ * T_) / 256, 256, 0, stream>>>(x, rn, nrm, Z, cnt);
    k_gather<<<(B_ * C_ * SCOLS_) / 256, 256, 0, stream>>>(x, rn, xs);
    k_msub2<<<dim3(SCOLS_ / 64, E_ / 64, B_), 256, 0, stream>>>(xs, mask_w, mask_b, msub);
    k_tau<<<B_, 256, 0, stream>>>(msub, tau0);
    if (fast) {
        k_split_w<<<(E_ * C_ / 4) / 256, 256, 0, stream>>>(mask_w, mwh, mwl);
        k_split_x<<<dim3(T_ / 64, C_ / 64, B_), 256, 0, stream>>>(x, rn, xh, xl);
        k_gemmf<<<(E_ / 64) * (T_ / 64) * B_, 256, 0, stream>>>(
            mwh, mwl, xh, xl, mask_b, tau0, Z, cnt, cval, cidx);
    } else {
        k_gemm<<<dim3(T_ / 64, E_ / 64, B_), 256, 0, stream>>>(
            x, mask_w, mask_b, rn, tau0, Z, cnt, cval, cidx);
    }
    k_select<<<B_, 256, 0, stream>>>(cval, cidx, cnt, Z, sel_e, sel_t, sel_sp);
    if (fast) {
        k_upg2<<<(B_ * K_ * 64) / 256, 256, 0, stream>>>(xh, xl, nrm, up_w, up_b,
                                                         sel_e, sel_t, sel_sp, gval);
    } else {
        k_upg<<<(B_ * K_ * 64) / 256, 256, 0, stream>>>(x, up_w, up_b, sel_e, sel_t,
                                                        sel_sp, gval);
    }
    k_bsq<<<(B_ * C_) / 4, 256, 0, stream>>>(sum_w, sum_b, down_b, down_w,
                                             sel_e, gval, base, S1, Qv);
    k_bnstats<<<1, C_, 0, stream>>>(base, S1, Qv, bn_w, bn_b, scalec, obase);
    k_fill<<<(B_ * CT_ / 4) / 256, 256, 0, stream>>>(obase, out);
    k_spikes<<<(B_ * K_ * 64) / 256, 256, 0, stream>>>(down_w, scalec, sel_e, sel_t,
                                                       gval, out);
}